// Round 12
// baseline (155.082 us; speedup 1.0000x reference)
//
#include <hip/hip_runtime.h>
#include <hip/hip_bf16.h>

// Problem constants
#define DIMD 1024
#define NH   16
#define NKV  4
#define HDIM 64
#define WINSZ 512
#define BB   4
#define TT   2048
#define MROWS (BB*TT)      // 8192
#define NQKV 1536

typedef __attribute__((ext_vector_type(8))) short short8;
typedef __attribute__((ext_vector_type(4))) float f32x4;

static __device__ __forceinline__ short f2bf(float f) {
  __hip_bfloat16 h = __float2bfloat16(f);
  return __builtin_bit_cast(short, h);
}
static __device__ __forceinline__ float bf2f(short s) {
  return __bfloat162float(__builtin_bit_cast(__hip_bfloat16, s));
}
static __device__ __forceinline__ unsigned pk2(float a, float b) {
  unsigned lo = (unsigned short)f2bf(a);
  unsigned hi = (unsigned short)f2bf(b);
  return lo | (hi << 16);
}

static __device__ __forceinline__ void gld_lds16(const void* g, void* l) {
  __builtin_amdgcn_global_load_lds(
      (const __attribute__((address_space(1))) unsigned int*)g,
      (__attribute__((address_space(3))) unsigned int*)l, 16, 0, 0);
}

// DPP rotate-right within each 16-lane row
template<int N>
static __device__ __forceinline__ float dpp_ror(float x) {
  return __builtin_bit_cast(float, __builtin_amdgcn_update_dpp(
      0, __builtin_bit_cast(int, x), 0x120 + N, 0xF, 0xF, true));
}

// ---------------------------------------------------------------------------
// 1) f32 -> bf16 conversion for x, wq|wk|wv (packed), wo.  Unit = 4 floats.
__global__ __launch_bounds__(256) void cvt_all_kernel(
    const float* __restrict__ x, const float* __restrict__ wq,
    const float* __restrict__ wk, const float* __restrict__ wv,
    const float* __restrict__ wo,
    short* __restrict__ xb, short* __restrict__ wqkvb, short* __restrict__ wob) {
  size_t u = (size_t)blockIdx.x * 256 + threadIdx.x;
  const float* src; short* dst;
  if (u < 2097152)                   { src = x;  dst = xb; }
  else if ((u -= 2097152) < 262144)  { src = wq; dst = wqkvb; }
  else if ((u -= 262144) < 65536)    { src = wk; dst = wqkvb + 1024*1024; }
  else if ((u -= 65536) < 65536)     { src = wv; dst = wqkvb + 1280*1024; }
  else { u -= 65536;                   src = wo; dst = wob; }
  float4 v = ((const float4*)src)[u];
  short4 o;
  o.x = f2bf(v.x); o.y = f2bf(v.y); o.z = f2bf(v.z); o.w = f2bf(v.w);
  ((short4*)dst)[u] = o;
}

// ---------------------------------------------------------------------------
// 2a) QKV GEMM with FUSED QK-RMSNorm epilogue.
//     C[8192][1536] = xb * wqkvb^T.  Each wave's 64-col span = one head slot
//     s = ccol0/64: s<16 -> Q head, s<20 -> K head, else V.
//     Q/K: in-register RMSNorm on f32 acc (4-step dpp row reduce over the 16
//     l15 lanes x 4 ni = 64 cols), write bf16 direct to Qh/Kh.
//     V: compact coalesced Vbuf[8192][256].  qkv buffer + qk_norm kernel gone.
#define BMT 128
#define BNT 128
#define BKT 64

__global__ __launch_bounds__(256) void gemm_qkv(
    const short* __restrict__ A, const short* __restrict__ Bw,
    const float* __restrict__ qw, const float* __restrict__ kw,
    short* __restrict__ Qh, short* __restrict__ Kh, short* __restrict__ Vbuf) {
  const int M = MROWS, N = NQKV, K = DIMD;
  __shared__ __align__(16) short As[BMT*BKT];
  __shared__ __align__(16) short Bs[BNT*BKT];

  int nwg  = gridDim.x;
  int orig = blockIdx.x;
  int wg   = (orig & 7) * (nwg >> 3) + (orig >> 3);   // XCD swizzle (nwg%8==0)
  int tiles_n = N / BNT;
  int m0 = (wg / tiles_n) * BMT;
  int n0 = (wg % tiles_n) * BNT;

  int tid = threadIdx.x;
  int lane = tid & 63, wv = tid >> 6;
  int l15 = lane & 15, lg = lane >> 4;
  int wr = wv >> 1, wc = wv & 1;

  f32x4 acc[4][4] = {};

  for (int k0 = 0; k0 < K; k0 += BKT) {
    __syncthreads();
    const char* Abase = (const char*)(A + (size_t)m0 * K + k0);
    const char* Bbase = (const char*)(Bw + (size_t)n0 * K + k0);
#pragma unroll
    for (int i = 0; i < 4; ++i) {
      int idx = i * 256 + tid;
      int row = idx >> 3;
      int cb  = (idx & 7) << 4;
      int scb = cb ^ ((row & 7) << 4);
      gld_lds16(Abase + (size_t)row * (K * 2) + scb,
                (char*)As + ((i * 256 + wv * 64) << 4));
      gld_lds16(Bbase + (size_t)row * (K * 2) + scb,
                (char*)Bs + ((i * 256 + wv * 64) << 4));
    }
    __syncthreads();

#pragma unroll
    for (int kk = 0; kk < 2; ++kk) {
      short8 af[4], bfr[4];
      int kb = (kk * 32 + lg * 8) * 2;
#pragma unroll
      for (int mi = 0; mi < 4; ++mi) {
        int row = wr * 64 + mi * 16 + l15;
        af[mi] = *(const short8*)((const char*)As + row * 128 + (kb ^ ((row & 7) << 4)));
      }
#pragma unroll
      for (int ni = 0; ni < 4; ++ni) {
        int row = wc * 64 + ni * 16 + l15;
        bfr[ni] = *(const short8*)((const char*)Bs + row * 128 + (kb ^ ((row & 7) << 4)));
      }
#pragma unroll
      for (int mi = 0; mi < 4; ++mi)
#pragma unroll
        for (int ni = 0; ni < 4; ++ni)
          acc[mi][ni] = __builtin_amdgcn_mfma_f32_16x16x32_bf16(af[mi], bfr[ni], acc[mi][ni], 0, 0, 0);
    }
  }

  int crow0 = m0 + wr * 64, ccol0 = n0 + wc * 64;
  int s = ccol0 >> 6;                    // head slot 0..23
  if (s < 20) {
    const float* wptr = (s < 16) ? qw : kw;
    float wl0 = wptr[l15],      wl1 = wptr[16 + l15];
    float wl2 = wptr[32 + l15], wl3 = wptr[48 + l15];
    short* hout = (s < 16) ? Qh : Kh;
    int hidx = (s < 16) ? s : (s - 16);
    int nheads = (s < 16) ? NH : NKV;
#pragma unroll
    for (int mi = 0; mi < 4; ++mi)
#pragma unroll
      for (int r = 0; r < 4; ++r) {
        float a0 = acc[mi][0][r], a1 = acc[mi][1][r];
        float a2 = acc[mi][2][r], a3 = acc[mi][3][r];
        float ssq = a0 * a0 + a1 * a1 + a2 * a2 + a3 * a3;
        ssq += dpp_ror<1>(ssq); ssq += dpp_ror<2>(ssq);
        ssq += dpp_ror<4>(ssq); ssq += dpp_ror<8>(ssq);
        float rn = rsqrtf(ssq * (1.0f / 64.0f) + 1e-6f);
        int trow = crow0 + mi * 16 + lg * 4 + r;
        int b = trow >> 11, tt = trow & 2047;
        short* op = hout + (((size_t)b * nheads + hidx) * TT + tt) * HDIM;
        op[l15]      = f2bf(a0 * rn * wl0);
        op[16 + l15] = f2bf(a1 * rn * wl1);
        op[32 + l15] = f2bf(a2 * rn * wl2);
        op[48 + l15] = f2bf(a3 * rn * wl3);
      }
  } else {
    int vc0 = ccol0 - 1280;
#pragma unroll
    for (int mi = 0; mi < 4; ++mi)
#pragma unroll
      for (int ni = 0; ni < 4; ++ni)
#pragma unroll
        for (int r = 0; r < 4; ++r) {
          int trow = crow0 + mi * 16 + lg * 4 + r;
          Vbuf[(size_t)trow * 256 + vc0 + ni * 16 + l15] = f2bf(acc[mi][ni][r]);
        }
  }
}

// ---------------------------------------------------------------------------
// 2b) Output GEMM  C[M][N] = A[M][K] * B[N][K]^T  (f32 out)
__global__ __launch_bounds__(256) void gemm_out(
    const short* __restrict__ A, const short* __restrict__ Bw,
    float* __restrict__ Cout, int M, int N, int K) {
  __shared__ __align__(16) short As[BMT*BKT];
  __shared__ __align__(16) short Bs[BNT*BKT];

  int nwg  = gridDim.x;
  int orig = blockIdx.x;
  int wg   = (orig & 7) * (nwg >> 3) + (orig >> 3);
  int tiles_n = N / BNT;
  int m0 = (wg / tiles_n) * BMT;
  int n0 = (wg % tiles_n) * BNT;

  int tid = threadIdx.x;
  int lane = tid & 63, wv = tid >> 6;
  int l15 = lane & 15, lg = lane >> 4;
  int wr = wv >> 1, wc = wv & 1;

  f32x4 acc[4][4] = {};

  for (int k0 = 0; k0 < K; k0 += BKT) {
    __syncthreads();
    const char* Abase = (const char*)(A + (size_t)m0 * K + k0);
    const char* Bbase = (const char*)(Bw + (size_t)n0 * K + k0);
#pragma unroll
    for (int i = 0; i < 4; ++i) {
      int idx = i * 256 + tid;
      int row = idx >> 3;
      int cb  = (idx & 7) << 4;
      int scb = cb ^ ((row & 7) << 4);
      gld_lds16(Abase + (size_t)row * (K * 2) + scb,
                (char*)As + ((i * 256 + wv * 64) << 4));
      gld_lds16(Bbase + (size_t)row * (K * 2) + scb,
                (char*)Bs + ((i * 256 + wv * 64) << 4));
    }
    __syncthreads();

#pragma unroll
    for (int kk = 0; kk < 2; ++kk) {
      short8 af[4], bfr[4];
      int kb = (kk * 32 + lg * 8) * 2;
#pragma unroll
      for (int mi = 0; mi < 4; ++mi) {
        int row = wr * 64 + mi * 16 + l15;
        af[mi] = *(const short8*)((const char*)As + row * 128 + (kb ^ ((row & 7) << 4)));
      }
#pragma unroll
      for (int ni = 0; ni < 4; ++ni) {
        int row = wc * 64 + ni * 16 + l15;
        bfr[ni] = *(const short8*)((const char*)Bs + row * 128 + (kb ^ ((row & 7) << 4)));
      }
#pragma unroll
      for (int mi = 0; mi < 4; ++mi)
#pragma unroll
        for (int ni = 0; ni < 4; ++ni)
          acc[mi][ni] = __builtin_amdgcn_mfma_f32_16x16x32_bf16(af[mi], bfr[ni], acc[mi][ni], 0, 0, 0);
    }
  }

  int crow0 = m0 + wr * 64, ccol0 = n0 + wc * 64;
#pragma unroll
  for (int mi = 0; mi < 4; ++mi)
#pragma unroll
    for (int ni = 0; ni < 4; ++ni)
#pragma unroll
      for (int r = 0; r < 4; ++r) {
        int row = crow0 + mi * 16 + lg * 4 + r;
        int col = ccol0 + ni * 16 + l15;
        Cout[(size_t)row * N + col] = acc[mi][ni][r];
      }
}

// ---------------------------------------------------------------------------
// 4) V transpose: Vbuf [8192][256] -> Vt [B][KV][64][T] (bf16)
__global__ __launch_bounds__(256) void vtrans_kernel(
    const short* __restrict__ Vbuf, short* __restrict__ Vt) {
  int tb = blockIdx.x, kv = blockIdx.y, b = blockIdx.z;
  __shared__ short tile[64][72];
  int tid = threadIdx.x;
#pragma unroll
  for (int i = 0; i < 2; ++i) {
    int idx = i * 256 + tid;
    int tr = idx >> 3;
    int c8 = (idx & 7) * 8;
    int t = tb * 64 + tr;
    const short* src = Vbuf + (size_t)(b * TT + t) * 256 + kv * 64 + c8;
    short8 v = *(const short8*)src;
#pragma unroll
    for (int j = 0; j < 8; ++j) tile[tr][c8 + j] = v[j];
  }
  __syncthreads();
#pragma unroll
  for (int i = 0; i < 2; ++i) {
    int idx = i * 256 + tid;
    int d = idx >> 3;
    int t8 = (idx & 7) * 8;
    short8 o;
#pragma unroll
    for (int j = 0; j < 8; ++j) o[j] = tile[t8 + j][d];
    short* dst = Vt + (((size_t)(b * NKV + kv) * HDIM) + d) * TT + tb * 64 + t8;
    *(short8*)dst = o;
  }
}

// ---------------------------------------------------------------------------
// 5) Sliding-window causal flash attention (GQA).
//    2 waves/block (128 thr) = 1 q-pair x 2 k-halves; 32 q/wave.
//    Swapped QK^T, fixed-max softmax, V loads at tile top.
//    NEW: 2-phase K-prefetch pipeline — next tile's K fragments are issued
//    before the current tile's softmax/PV, hiding K latency (T14).
#define C1A 0.180336880f   // 0.125 * log2(e)
#define C2A 11.5415603f    // 8     * log2(e)

__global__ __launch_bounds__(128) void attn_kernel(
    const short* __restrict__ Qh, const short* __restrict__ Kh,
    const short* __restrict__ Vt, short* __restrict__ Y) {
  int wgid = blockIdx.x;
  int qh = wgid >> 6;                  // 0..63, SLOWEST (per-CU balance)
  int hb = wgid & 63;
  int h = hb >> 2, b = hb & 3;
  int tid = threadIdx.x, lane = tid & 63;
  int khalf = tid >> 6;                // wave 0 = low k-half, wave 1 = high
  int l15 = lane & 15, lg = lane >> 4;
  int kvh = h >> 2;
  int q0 = qh * 32;                    // this block's 32 q rows
  const short* Qp = Qh + (((size_t)b * NH + h) * TT + q0) * HDIM;
  const short* Kp = Kh + ((size_t)b * NKV + kvh) * TT * HDIM;
  const short* Vp = Vt + ((size_t)b * NKV + kvh) * HDIM * TT;

  short8 aqA0 = *(const short8*)(Qp + l15 * HDIM + lg * 8);
  short8 aqA1 = *(const short8*)(Qp + l15 * HDIM + 32 + lg * 8);
  short8 aqB0 = *(const short8*)(Qp + (16 + l15) * HDIM + lg * 8);
  short8 aqB1 = *(const short8*)(Qp + (16 + l15) * HDIM + 32 + lg * 8);

  float lpA = 0.f, lpB = 0.f;          // lane-scalar partials (q = l15)
  f32x4 yA[4] = {}, yB[4] = {};

  __shared__ __align__(16) char smem[9216];
  short* PA = (short*)smem + khalf * 2304;       // 16 x 72
  short* PB = PA + 1152;

  int lo = q0 - (WINSZ - 1); if (lo < 0) lo = 0;
  int klo = lo & ~63;
  int nt = (q0 + 32 - klo + 63) >> 6;  // CEIL tile count
  int tmid = (nt + 1) >> 1;
  int t0 = khalf ? tmid : 0;
  int t1 = khalf ? nt : tmid;

  int qiA = q0 + l15, qiB = qiA + 16;

  auto LOADK = [&](int kc, short8 (&bk0)[4], short8 (&bk1)[4]) {
#pragma unroll
    for (int nc = 0; nc < 4; ++nc) {
      const short* kb = Kp + (size_t)(kc + nc * 16 + l15) * HDIM + lg * 8;
      bk0[nc] = *(const short8*)kb;
      bk1[nc] = *(const short8*)(kb + 32);
    }
  };

  auto PROC = [&](int kc, short8 (&bk0)[4], short8 (&bk1)[4]) {
    // V fragments (latency hidden under QK + softmax)
    short8 bv0[4], bv1[4];
#pragma unroll
    for (int dt = 0; dt < 4; ++dt) {
      const short* vb = Vp + (size_t)(dt * 16 + l15) * TT + kc + lg * 8;
      bv0[dt] = *(const short8*)vb;
      bv1[dt] = *(const short8*)(vb + 32);
    }
    // swapped QK^T: D[k][q]
    f32x4 sA[4], sB[4];
#pragma unroll
    for (int nc = 0; nc < 4; ++nc) {
      f32x4 zA = {}, zB = {};
      zA = __builtin_amdgcn_mfma_f32_16x16x32_bf16(bk0[nc], aqA0, zA, 0, 0, 0);
      zB = __builtin_amdgcn_mfma_f32_16x16x32_bf16(bk0[nc], aqB0, zB, 0, 0, 0);
      zA = __builtin_amdgcn_mfma_f32_16x16x32_bf16(bk1[nc], aqA1, zA, 0, 0, 0);
      zB = __builtin_amdgcn_mfma_f32_16x16x32_bf16(bk1[nc], aqB1, zB, 0, 0, 0);
      sA[nc] = zA; sB[nc] = zB;
    }
    // fixed-max softmax, pack, vector LDS write (k-major per lane)
    bool intA = (kc >= q0 - 496) && (kc + 63 <= q0);
    bool intB = (kc >= q0 - 480) && (kc + 63 <= q0 + 16);
    if (intA && intB) {
#pragma unroll
      for (int nc = 0; nc < 4; ++nc) {
        float pa0 = __builtin_amdgcn_exp2f(fmaf(sA[nc][0], C1A, -C2A));
        float pa1 = __builtin_amdgcn_exp2f(fmaf(sA[nc][1], C1A, -C2A));
        float pa2 = __builtin_amdgcn_exp2f(fmaf(sA[nc][2], C1A, -C2A));
        float pa3 = __builtin_amdgcn_exp2f(fmaf(sA[nc][3], C1A, -C2A));
        float pb0 = __builtin_amdgcn_exp2f(fmaf(sB[nc][0], C1A, -C2A));
        float pb1 = __builtin_amdgcn_exp2f(fmaf(sB[nc][1], C1A, -C2A));
        float pb2 = __builtin_amdgcn_exp2f(fmaf(sB[nc][2], C1A, -C2A));
        float pb3 = __builtin_amdgcn_exp2f(fmaf(sB[nc][3], C1A, -C2A));
        lpA += (pa0 + pa1) + (pa2 + pa3);
        lpB += (pb0 + pb1) + (pb2 + pb3);
        *(uint2*)(PA + l15 * 72 + nc * 16 + lg * 4) = uint2{pk2(pa0, pa1), pk2(pa2, pa3)};
        *(uint2*)(PB + l15 * 72 + nc * 16 + lg * 4) = uint2{pk2(pb0, pb1), pk2(pb2, pb3)};
      }
    } else {
      int kjb = kc + lg * 4;
#pragma unroll
      for (int nc = 0; nc < 4; ++nc) {
        float pa[4], pb[4];
#pragma unroll
        for (int r = 0; r < 4; ++r) {
          int kj = kjb + nc * 16 + r;
          bool okA = (kj <= qiA) && (qiA - kj < WINSZ);
          bool okB = (kj <= qiB) && (qiB - kj < WINSZ);
          pa[r] = okA ? __builtin_amdgcn_exp2f(fmaf(sA[nc][r], C1A, -C2A)) : 0.f;
          pb[r] = okB ? __builtin_amdgcn_exp2f(fmaf(sB[nc][r], C1A, -C2A)) : 0.f;
        }
        lpA += (pa[0] + pa[1]) + (pa[2] + pa[3]);
        lpB += (pb[0] + pb[1]) + (pb[2] + pb[3]);
        *(uint2*)(PA + l15 * 72 + nc * 16 + lg * 4) = uint2{pk2(pa[0], pa[1]), pk2(pa[2], pa[3])};
        *(uint2*)(PB + l15 * 72 + nc * 16 + lg * 4) = uint2{pk2(pb[0], pb[1]), pk2(pb[2], pb[3])};
      }
    }
    // PV A-fragments (per-wave LDS region, no barrier)
    short8 apA0 = *(const short8*)(PA + l15 * 72 + lg * 8);
    short8 apA1 = *(const short8*)(PA + l15 * 72 + 32 + lg * 8);
    short8 apB0 = *(const short8*)(PB + l15 * 72 + lg * 8);
    short8 apB1 = *(const short8*)(PB + l15 * 72 + 32 + lg * 8);
#pragma unroll
    for (int dt = 0; dt < 4; ++dt) {
      yA[dt] = __builtin_amdgcn_mfma_f32_16x16x32_bf16(apA0, bv0[dt], yA[dt], 0, 0, 0);
      yB[dt] = __builtin_amdgcn_mfma_f32_16x16x32_bf16(apB0, bv0[dt], yB[dt], 0, 0, 0);
      yA[dt] = __builtin_amdgcn_mfma_f32_16x16x32_bf16(apA1, bv1[dt], yA[dt], 0, 0, 0);
      yB[dt] = __builtin_amdgcn_mfma_f32_16x16x32_bf16(apB1, bv1[dt], yB[dt], 0, 0, 0);
    }
  };

  // ---- 2-phase K-prefetch pipeline (static buffers, no runtime indexing)
  short8 kA0[4], kA1[4], kB0[4], kB1[4];
  int kc = klo + t0 * 64;
  if (t0 < t1) LOADK(kc, kA0, kA1);
  for (int t = t0; t < t1; t += 2) {
    if (t + 1 < t1) LOADK(kc + 64, kB0, kB1);     // prefetch next tile's K
    PROC(kc, kA0, kA1);
    if (t + 2 < t1) LOADK(kc + 128, kA0, kA1);    // prefetch tile t+2
    if (t + 1 < t1) PROC(kc + 64, kB0, kB1);
    kc += 128;
  }

  // ---- reduce lane-scalar denominators across the 4 lg copies (q = l15)
  lpA += __shfl_xor(lpA, 16); lpA += __shfl_xor(lpA, 32);
  lpB += __shfl_xor(lpB, 16); lpB += __shfl_xor(lpB, 32);

  // ---- combine k-halves across the 2 waves
  __syncthreads();
  f32x4* ybuf = (f32x4*)smem;
  float* lbufA = (float*)(smem + 8192);
  float* lbufB = lbufA + 16;
  if (khalf) {
#pragma unroll
    for (int dt = 0; dt < 4; ++dt) {
      ybuf[dt * 64 + lane] = yA[dt];
      ybuf[(4 + dt) * 64 + lane] = yB[dt];
    }
    if (lg == 0) { lbufA[l15] = lpA; lbufB[l15] = lpB; }
  }
  __syncthreads();
  if (!khalf) {
#pragma unroll
    for (int dt = 0; dt < 4; ++dt) {
      f32x4 pa = ybuf[dt * 64 + lane];
      f32x4 pb = ybuf[(4 + dt) * 64 + lane];
#pragma unroll
      for (int r = 0; r < 4; ++r) { yA[dt][r] += pa[r]; yB[dt][r] += pb[r]; }
    }
    float invqA = 1.0f / (lpA + lbufA[l15]);   // q = l15
    float invqB = 1.0f / (lpB + lbufB[l15]);
#pragma unroll
    for (int r = 0; r < 4; ++r) {
      float invA = __builtin_bit_cast(float, __builtin_amdgcn_ds_bpermute(
          (lg * 4 + r) << 2, __builtin_bit_cast(int, invqA)));
      float invB = __builtin_bit_cast(float, __builtin_amdgcn_ds_bpermute(
          (lg * 4 + r) << 2, __builtin_bit_cast(int, invqB)));
      int qiAo = q0 + lg * 4 + r, qiBo = qiAo + 16;
#pragma unroll
      for (int dt = 0; dt < 4; ++dt) {
        Y[((size_t)(b * TT + qiAo)) * DIMD + h * HDIM + dt * 16 + l15] = f2bf(yA[dt][r] * invA);
        Y[((size_t)(b * TT + qiBo)) * DIMD + h * HDIM + dt * 16 + l15] = f2bf(yB[dt][r] * invB);
      }
    }
  }
}

// ---------------------------------------------------------------------------
extern "C" void kernel_launch(void* const* d_in, const int* in_sizes, int n_in,
                              void* d_out, int out_size, void* d_ws, size_t ws_size,
                              hipStream_t stream) {
  const float* x  = (const float*)d_in[0];
  const float* wq = (const float*)d_in[1];
  const float* wk = (const float*)d_in[2];
  const float* wv = (const float*)d_in[3];
  const float* wo = (const float*)d_in[4];
  const float* qw = (const float*)d_in[5];
  const float* kw = (const float*)d_in[6];

  char* ws = (char*)d_ws;
  short* xb    = (short*)(ws + 0);            // 16 MB  [8192][1024] bf16
  short* wqkvb = (short*)(ws + 16777216);     // 3 MB   [1536][1024]
  short* wob   = (short*)(ws + 19922944);     // 2 MB   [1024][1024]
  short* Vbuf  = (short*)(ws + 22020096);     // 4 MB   [8192][256]
  short* Qh    = (short*)(ws + 26214400);     // 16 MB  [B][H][T][64]
  short* Kh    = (short*)(ws + 42991616);     // 4 MB   [B][KV][T][64]
  short* Vt    = (short*)(ws + 47185920);     // 4 MB   [B][KV][64][T]
  short* Y     = xb;                          // alias: xb dead after QKV GEMM
  float* outp  = (float*)d_out;

  cvt_all_kernel<<<10752, 256, 0, stream>>>(x, wq, wk, wv, wo, xb, wqkvb, wob);
  gemm_qkv<<<768, 256, 0, stream>>>(xb, wqkvb, qw, kw, Qh, Kh, Vbuf);
  vtrans_kernel<<<dim3(32, 4, 4), 256, 0, stream>>>(Vbuf, Vt);
  attn_kernel<<<4096, 128, 0, stream>>>(Qh, Kh, Vt, Y);
  gemm_out<<<512, 256, 0, stream>>>(Y, wob, outp, MROWS, DIMD, DIMD);
}

// Round 13
// 151.883 us; speedup vs baseline: 1.0211x; 1.0211x over previous
//
#include <hip/hip_runtime.h>
#include <hip/hip_bf16.h>

// Problem constants
#define DIMD 1024
#define NH   16
#define NKV  4
#define HDIM 64
#define WINSZ 512
#define BB   4
#define TT   2048
#define MROWS (BB*TT)      // 8192
#define NQKV 1536

typedef __attribute__((ext_vector_type(8))) short short8;
typedef __attribute__((ext_vector_type(4))) float f32x4;

static __device__ __forceinline__ short f2bf(float f) {
  __hip_bfloat16 h = __float2bfloat16(f);
  return __builtin_bit_cast(short, h);
}
static __device__ __forceinline__ float bf2f(short s) {
  return __bfloat162float(__builtin_bit_cast(__hip_bfloat16, s));
}
static __device__ __forceinline__ unsigned pk2(float a, float b) {
  unsigned lo = (unsigned short)f2bf(a);
  unsigned hi = (unsigned short)f2bf(b);
  return lo | (hi << 16);
}

static __device__ __forceinline__ void gld_lds16(const void* g, void* l) {
  __builtin_amdgcn_global_load_lds(
      (const __attribute__((address_space(1))) unsigned int*)g,
      (__attribute__((address_space(3))) unsigned int*)l, 16, 0, 0);
}

// DPP rotate-right within each 16-lane row
template<int N>
static __device__ __forceinline__ float dpp_ror(float x) {
  return __builtin_bit_cast(float, __builtin_amdgcn_update_dpp(
      0, __builtin_bit_cast(int, x), 0x120 + N, 0xF, 0xF, true));
}

// ---------------------------------------------------------------------------
// 1) f32 -> bf16 conversion for x, wq|wk|wv (packed), wo.  Unit = 4 floats.
__global__ __launch_bounds__(256) void cvt_all_kernel(
    const float* __restrict__ x, const float* __restrict__ wq,
    const float* __restrict__ wk, const float* __restrict__ wv,
    const float* __restrict__ wo,
    short* __restrict__ xb, short* __restrict__ wqkvb, short* __restrict__ wob) {
  size_t u = (size_t)blockIdx.x * 256 + threadIdx.x;
  const float* src; short* dst;
  if (u < 2097152)                   { src = x;  dst = xb; }
  else if ((u -= 2097152) < 262144)  { src = wq; dst = wqkvb; }
  else if ((u -= 262144) < 65536)    { src = wk; dst = wqkvb + 1024*1024; }
  else if ((u -= 65536) < 65536)     { src = wv; dst = wqkvb + 1280*1024; }
  else { u -= 65536;                   src = wo; dst = wob; }
  float4 v = ((const float4*)src)[u];
  short4 o;
  o.x = f2bf(v.x); o.y = f2bf(v.y); o.z = f2bf(v.z); o.w = f2bf(v.w);
  ((short4*)dst)[u] = o;
}

// ---------------------------------------------------------------------------
// 2) GEMM  C[M][N] = A[M][K] * B[N][K]^T   (bf16 in, bf16 or f32 out)
#define BMT 128
#define BNT 128
#define BKT 64

template<bool OUT_BF16>
__global__ __launch_bounds__(256) void gemm_bt(
    const short* __restrict__ A, const short* __restrict__ Bw,
    void* __restrict__ Cout, int M, int N, int K) {
  __shared__ __align__(16) short As[BMT*BKT];
  __shared__ __align__(16) short Bs[BNT*BKT];

  int nwg  = gridDim.x;
  int orig = blockIdx.x;
  int wg   = (orig & 7) * (nwg >> 3) + (orig >> 3);   // XCD swizzle (nwg%8==0)
  int tiles_n = N / BNT;
  int m0 = (wg / tiles_n) * BMT;
  int n0 = (wg % tiles_n) * BNT;

  int tid = threadIdx.x;
  int lane = tid & 63, wv = tid >> 6;
  int l15 = lane & 15, lg = lane >> 4;
  int wr = wv >> 1, wc = wv & 1;

  f32x4 acc[4][4] = {};

  for (int k0 = 0; k0 < K; k0 += BKT) {
    __syncthreads();
    const char* Abase = (const char*)(A + (size_t)m0 * K + k0);
    const char* Bbase = (const char*)(Bw + (size_t)n0 * K + k0);
#pragma unroll
    for (int i = 0; i < 4; ++i) {
      int idx = i * 256 + tid;
      int row = idx >> 3;
      int cb  = (idx & 7) << 4;
      int scb = cb ^ ((row & 7) << 4);
      gld_lds16(Abase + (size_t)row * (K * 2) + scb,
                (char*)As + ((i * 256 + wv * 64) << 4));
      gld_lds16(Bbase + (size_t)row * (K * 2) + scb,
                (char*)Bs + ((i * 256 + wv * 64) << 4));
    }
    __syncthreads();

#pragma unroll
    for (int kk = 0; kk < 2; ++kk) {
      short8 af[4], bfr[4];
      int kb = (kk * 32 + lg * 8) * 2;
#pragma unroll
      for (int mi = 0; mi < 4; ++mi) {
        int row = wr * 64 + mi * 16 + l15;
        af[mi] = *(const short8*)((const char*)As + row * 128 + (kb ^ ((row & 7) << 4)));
      }
#pragma unroll
      for (int ni = 0; ni < 4; ++ni) {
        int row = wc * 64 + ni * 16 + l15;
        bfr[ni] = *(const short8*)((const char*)Bs + row * 128 + (kb ^ ((row & 7) << 4)));
      }
#pragma unroll
      for (int mi = 0; mi < 4; ++mi)
#pragma unroll
        for (int ni = 0; ni < 4; ++ni)
          acc[mi][ni] = __builtin_amdgcn_mfma_f32_16x16x32_bf16(af[mi], bfr[ni], acc[mi][ni], 0, 0, 0);
    }
  }

  int crow0 = m0 + wr * 64, ccol0 = n0 + wc * 64;
#pragma unroll
  for (int mi = 0; mi < 4; ++mi)
#pragma unroll
    for (int ni = 0; ni < 4; ++ni)
#pragma unroll
      for (int r = 0; r < 4; ++r) {
        int row = crow0 + mi * 16 + lg * 4 + r;
        int col = ccol0 + ni * 16 + l15;
        float v = acc[mi][ni][r];
        if (OUT_BF16) ((short*)Cout)[(size_t)row * N + col] = f2bf(v);
        else          ((float*)Cout)[(size_t)row * N + col] = v;
      }
}

// ---------------------------------------------------------------------------
// 3) RMSNorm on q and k heads; one 16-lane group per head-row, lane holds 4.
__global__ __launch_bounds__(256) void qk_norm_kernel(
    const short* __restrict__ qkv, const float* __restrict__ qw,
    const float* __restrict__ kw, short* __restrict__ Qh, short* __restrict__ Kh) {
  unsigned gid = blockIdx.x * 16u + (threadIdx.x >> 4);
  int l = threadIdx.x & 15;
  unsigned row = gid / 20u;          // b*T + t
  int s = (int)(gid - row * 20u);    // head slot 0..19
  int b = row >> 11, t = row & 2047;
  bool isq = s < 16;
  int col = isq ? s * 64 : 1024 + (s - 16) * 64;
  const short* rp = qkv + (size_t)row * NQKV + col + l * 4;
  short4 v4 = *(const short4*)rp;
  float f0 = bf2f(v4.x), f1 = bf2f(v4.y), f2 = bf2f(v4.z), f3 = bf2f(v4.w);
  float ss = f0 * f0 + f1 * f1 + f2 * f2 + f3 * f3;
  ss += dpp_ror<1>(ss); ss += dpp_ror<2>(ss);
  ss += dpp_ror<4>(ss); ss += dpp_ror<8>(ss);
  float r = rsqrtf(ss * (1.0f / 64.0f) + 1e-6f);
  float4 w4 = *(const float4*)((isq ? qw : kw) + l * 4);
  short4 o;
  o.x = f2bf(f0 * r * w4.x); o.y = f2bf(f1 * r * w4.y);
  o.z = f2bf(f2 * r * w4.z); o.w = f2bf(f3 * r * w4.w);
  if (isq) *(short4*)(Qh + (((size_t)b * NH + s) * TT + t) * HDIM + l * 4) = o;
  else     *(short4*)(Kh + (((size_t)b * NKV + (s - 16)) * TT + t) * HDIM + l * 4) = o;
}

// ---------------------------------------------------------------------------
// 4) V transpose: qkv cols [1280..1536) -> Vt [B][KV][64][T] (bf16)
__global__ __launch_bounds__(256) void vtrans_kernel(
    const short* __restrict__ qkv, short* __restrict__ Vt) {
  int tb = blockIdx.x, kv = blockIdx.y, b = blockIdx.z;
  __shared__ short tile[64][72];
  int tid = threadIdx.x;
#pragma unroll
  for (int i = 0; i < 2; ++i) {
    int idx = i * 256 + tid;
    int tr = idx >> 3;
    int c8 = (idx & 7) * 8;
    int t = tb * 64 + tr;
    const short* src = qkv + (size_t)(b * TT + t) * NQKV + 1280 + kv * 64 + c8;
    short8 v = *(const short8*)src;
#pragma unroll
    for (int j = 0; j < 8; ++j) tile[tr][c8 + j] = v[j];
  }
  __syncthreads();
#pragma unroll
  for (int i = 0; i < 2; ++i) {
    int idx = i * 256 + tid;
    int d = idx >> 3;
    int t8 = (idx & 7) * 8;
    short8 o;
#pragma unroll
    for (int j = 0; j < 8; ++j) o[j] = tile[t8 + j][d];
    short* dst = Vt + (((size_t)(b * NKV + kv) * HDIM) + d) * TT + tb * 64 + t8;
    *(short8*)dst = o;
  }
}

// ---------------------------------------------------------------------------
// 5) Sliding-window causal flash attention (GQA).
//    4 waves/block (256 thr) = same 32 q rows, K-SPLIT-4: wave w handles
//    tiles [(w*nt)>>2, ((w+1)*nt)>>2).  Halves the per-wave serial chain vs
//    k-split-2 (r5's biggest win), doubles wave count (16384).  Per-wave
//    structure identical to r11 (VGPR ~88, no prefetch — r12 showed VGPR>128
//    halves residency).  setprio(1) around MFMA clusters (T5, +4-7% attn).
//    Waves 1-3 store y/lp partials to LDS; wave 0 combines + writes.
#define C1A 0.180336880f   // 0.125 * log2(e)
#define C2A 11.5415603f    // 8     * log2(e)

__global__ __launch_bounds__(256) void attn_kernel(
    const short* __restrict__ Qh, const short* __restrict__ Kh,
    const short* __restrict__ Vt, short* __restrict__ Y) {
  int wgid = blockIdx.x;
  int qh = wgid >> 6;                  // 0..63, SLOWEST (per-CU balance)
  int hb = wgid & 63;
  int h = hb >> 2, b = hb & 3;
  int tid = threadIdx.x, lane = tid & 63;
  int wq4 = tid >> 6;                  // wave 0..3 = k-quarter
  int l15 = lane & 15, lg = lane >> 4;
  int kvh = h >> 2;
  int q0 = qh * 32;                    // this block's 32 q rows
  const short* Qp = Qh + (((size_t)b * NH + h) * TT + q0) * HDIM;
  const short* Kp = Kh + ((size_t)b * NKV + kvh) * TT * HDIM;
  const short* Vp = Vt + ((size_t)b * NKV + kvh) * HDIM * TT;

  short8 aqA0 = *(const short8*)(Qp + l15 * HDIM + lg * 8);
  short8 aqA1 = *(const short8*)(Qp + l15 * HDIM + 32 + lg * 8);
  short8 aqB0 = *(const short8*)(Qp + (16 + l15) * HDIM + lg * 8);
  short8 aqB1 = *(const short8*)(Qp + (16 + l15) * HDIM + 32 + lg * 8);

  float lpA = 0.f, lpB = 0.f;          // lane-scalar partials (q = l15)
  f32x4 yA[4] = {}, yB[4] = {};

  // LDS: P scratch (loop, 4x4608B=18432) overlaps combine bufs (24960B).
  __shared__ __align__(16) char smem[25088];
  short* PA = (short*)smem + wq4 * 2304;         // 16 x 72
  short* PB = PA + 1152;

  int lo = q0 - (WINSZ - 1); if (lo < 0) lo = 0;
  int klo = lo & ~63;
  int nt = (q0 + 32 - klo + 63) >> 6;  // CEIL tile count
  int t0 = (wq4 * nt) >> 2;            // telescoping union covers [0,nt)
  int t1 = ((wq4 + 1) * nt) >> 2;

  int qiA = q0 + l15, qiB = qiA + 16;  // q index per lane (swapped layout)

  for (int t = t0; t < t1; ++t) {
    int kc = klo + t * 64;
    // ---- K and V fragments both loaded up front (V hides under QK+softmax)
    short8 bk0[4], bk1[4], bv0[4], bv1[4];
#pragma unroll
    for (int nc = 0; nc < 4; ++nc) {
      const short* kb = Kp + (size_t)(kc + nc * 16 + l15) * HDIM + lg * 8;
      bk0[nc] = *(const short8*)kb;
      bk1[nc] = *(const short8*)(kb + 32);
    }
#pragma unroll
    for (int dt = 0; dt < 4; ++dt) {
      const short* vb = Vp + (size_t)(dt * 16 + l15) * TT + kc + lg * 8;
      bv0[dt] = *(const short8*)vb;
      bv1[dt] = *(const short8*)(vb + 32);
    }
    // ---- swapped QK^T: D[k][q]
    f32x4 sA[4], sB[4];
    __builtin_amdgcn_s_setprio(1);
#pragma unroll
    for (int nc = 0; nc < 4; ++nc) {
      f32x4 zA = {}, zB = {};
      zA = __builtin_amdgcn_mfma_f32_16x16x32_bf16(bk0[nc], aqA0, zA, 0, 0, 0);
      zB = __builtin_amdgcn_mfma_f32_16x16x32_bf16(bk0[nc], aqB0, zB, 0, 0, 0);
      zA = __builtin_amdgcn_mfma_f32_16x16x32_bf16(bk1[nc], aqA1, zA, 0, 0, 0);
      zB = __builtin_amdgcn_mfma_f32_16x16x32_bf16(bk1[nc], aqB1, zB, 0, 0, 0);
      sA[nc] = zA; sB[nc] = zB;
    }
    __builtin_amdgcn_s_setprio(0);
    // ---- fixed-max softmax, pack, vector LDS write (k-major per lane)
    bool intA = (kc >= q0 - 496) && (kc + 63 <= q0);
    bool intB = (kc >= q0 - 480) && (kc + 63 <= q0 + 16);
    if (intA && intB) {
#pragma unroll
      for (int nc = 0; nc < 4; ++nc) {
        float pa0 = __builtin_amdgcn_exp2f(fmaf(sA[nc][0], C1A, -C2A));
        float pa1 = __builtin_amdgcn_exp2f(fmaf(sA[nc][1], C1A, -C2A));
        float pa2 = __builtin_amdgcn_exp2f(fmaf(sA[nc][2], C1A, -C2A));
        float pa3 = __builtin_amdgcn_exp2f(fmaf(sA[nc][3], C1A, -C2A));
        float pb0 = __builtin_amdgcn_exp2f(fmaf(sB[nc][0], C1A, -C2A));
        float pb1 = __builtin_amdgcn_exp2f(fmaf(sB[nc][1], C1A, -C2A));
        float pb2 = __builtin_amdgcn_exp2f(fmaf(sB[nc][2], C1A, -C2A));
        float pb3 = __builtin_amdgcn_exp2f(fmaf(sB[nc][3], C1A, -C2A));
        lpA += (pa0 + pa1) + (pa2 + pa3);
        lpB += (pb0 + pb1) + (pb2 + pb3);
        *(uint2*)(PA + l15 * 72 + nc * 16 + lg * 4) = uint2{pk2(pa0, pa1), pk2(pa2, pa3)};
        *(uint2*)(PB + l15 * 72 + nc * 16 + lg * 4) = uint2{pk2(pb0, pb1), pk2(pb2, pb3)};
      }
    } else {
      int kjb = kc + lg * 4;
#pragma unroll
      for (int nc = 0; nc < 4; ++nc) {
        float pa[4], pb[4];
#pragma unroll
        for (int r = 0; r < 4; ++r) {
          int kj = kjb + nc * 16 + r;
          bool okA = (kj <= qiA) && (qiA - kj < WINSZ);
          bool okB = (kj <= qiB) && (qiB - kj < WINSZ);
          pa[r] = okA ? __builtin_amdgcn_exp2f(fmaf(sA[nc][r], C1A, -C2A)) : 0.f;
          pb[r] = okB ? __builtin_amdgcn_exp2f(fmaf(sB[nc][r], C1A, -C2A)) : 0.f;
        }
        lpA += (pa[0] + pa[1]) + (pa[2] + pa[3]);
        lpB += (pb[0] + pb[1]) + (pb[2] + pb[3]);
        *(uint2*)(PA + l15 * 72 + nc * 16 + lg * 4) = uint2{pk2(pa[0], pa[1]), pk2(pa[2], pa[3])};
        *(uint2*)(PB + l15 * 72 + nc * 16 + lg * 4) = uint2{pk2(pb[0], pb[1]), pk2(pb[2], pb[3])};
      }
    }
    // ---- PV A-fragments (per-wave LDS region, no barrier)
    short8 apA0 = *(const short8*)(PA + l15 * 72 + lg * 8);
    short8 apA1 = *(const short8*)(PA + l15 * 72 + 32 + lg * 8);
    short8 apB0 = *(const short8*)(PB + l15 * 72 + lg * 8);
    short8 apB1 = *(const short8*)(PB + l15 * 72 + 32 + lg * 8);
    __builtin_amdgcn_s_setprio(1);
#pragma unroll
    for (int dt = 0; dt < 4; ++dt) {
      yA[dt] = __builtin_amdgcn_mfma_f32_16x16x32_bf16(apA0, bv0[dt], yA[dt], 0, 0, 0);
      yB[dt] = __builtin_amdgcn_mfma_f32_16x16x32_bf16(apB0, bv0[dt], yB[dt], 0, 0, 0);
      yA[dt] = __builtin_amdgcn_mfma_f32_16x16x32_bf16(apA1, bv1[dt], yA[dt], 0, 0, 0);
      yB[dt] = __builtin_amdgcn_mfma_f32_16x16x32_bf16(apB1, bv1[dt], yB[dt], 0, 0, 0);
    }
    __builtin_amdgcn_s_setprio(0);
  }

  // ---- reduce lane-scalar denominators across the 4 lg copies (q = l15)
  lpA += __shfl_xor(lpA, 16); lpA += __shfl_xor(lpA, 32);
  lpB += __shfl_xor(lpB, 16); lpB += __shfl_xor(lpB, 32);

  // ---- combine k-quarters: waves 1-3 store partials; wave 0 sums
  __syncthreads();                       // everyone done with P region
  f32x4* ybuf = (f32x4*)smem;            // 3 waves x 512 f32x4 = 24576 B
  float* lbuf = (float*)(smem + 24576);  // 3 waves x 32 floats
  if (wq4) {
    int wb = (wq4 - 1) * 512;
#pragma unroll
    for (int dt = 0; dt < 4; ++dt) {
      ybuf[wb + dt * 64 + lane] = yA[dt];
      ybuf[wb + (4 + dt) * 64 + lane] = yB[dt];
    }
    if (lg == 0) {
      lbuf[(wq4 - 1) * 32 + l15] = lpA;
      lbuf[(wq4 - 1) * 32 + 16 + l15] = lpB;
    }
  }
  __syncthreads();
  if (wq4 == 0) {
#pragma unroll
    for (int w = 0; w < 3; ++w) {
#pragma unroll
      for (int dt = 0; dt < 4; ++dt) {
        f32x4 pa = ybuf[w * 512 + dt * 64 + lane];
        f32x4 pb = ybuf[w * 512 + (4 + dt) * 64 + lane];
#pragma unroll
        for (int r = 0; r < 4; ++r) { yA[dt][r] += pa[r]; yB[dt][r] += pb[r]; }
      }
      lpA += lbuf[w * 32 + l15];
      lpB += lbuf[w * 32 + 16 + l15];
    }
    float invqA = 1.0f / lpA;            // q = l15
    float invqB = 1.0f / lpB;
#pragma unroll
    for (int r = 0; r < 4; ++r) {
      // redistribute: y rows are q = lg*4+r -> pull inv from lane (lg*4+r)
      float invA = __builtin_bit_cast(float, __builtin_amdgcn_ds_bpermute(
          (lg * 4 + r) << 2, __builtin_bit_cast(int, invqA)));
      float invB = __builtin_bit_cast(float, __builtin_amdgcn_ds_bpermute(
          (lg * 4 + r) << 2, __builtin_bit_cast(int, invqB)));
      int qiAo = q0 + lg * 4 + r, qiBo = qiAo + 16;
#pragma unroll
      for (int dt = 0; dt < 4; ++dt) {
        Y[((size_t)(b * TT + qiAo)) * DIMD + h * HDIM + dt * 16 + l15] = f2bf(yA[dt][r] * invA);
        Y[((size_t)(b * TT + qiBo)) * DIMD + h * HDIM + dt * 16 + l15] = f2bf(yB[dt][r] * invB);
      }
    }
  }
}

// ---------------------------------------------------------------------------
extern "C" void kernel_launch(void* const* d_in, const int* in_sizes, int n_in,
                              void* d_out, int out_size, void* d_ws, size_t ws_size,
                              hipStream_t stream) {
  const float* x  = (const float*)d_in[0];
  const float* wq = (const float*)d_in[1];
  const float* wk = (const float*)d_in[2];
  const float* wv = (const float*)d_in[3];
  const float* wo = (const float*)d_in[4];
  const float* qw = (const float*)d_in[5];
  const float* kw = (const float*)d_in[6];

  char* ws = (char*)d_ws;
  short* xb    = (short*)(ws + 0);            // 16 MB  [8192][1024] bf16
  short* wqkvb = (short*)(ws + 16777216);     // 3 MB   [1536][1024]
  short* wob   = (short*)(ws + 19922944);     // 2 MB   [1024][1024]
  short* qkv   = (short*)(ws + 22020096);     // 24 MB  [8192][1536]
  short* Qh    = (short*)(ws + 47185920);     // 16 MB  [B][H][T][64]
  short* Kh    = (short*)(ws + 63963136);     // 4 MB   [B][KV][T][64]
  short* Vt    = (short*)(ws + 68157440);     // 4 MB   [B][KV][64][T]
  short* Y     = xb;                          // alias: xb dead after QKV GEMM
  float* outp  = (float*)d_out;

  cvt_all_kernel<<<10752, 256, 0, stream>>>(x, wq, wk, wv, wo, xb, wqkvb, wob);
  gemm_bt<true><<<dim3(64 * 12), 256, 0, stream>>>(xb, wqkvb, (void*)qkv, MROWS, NQKV, DIMD);
  qk_norm_kernel<<<10240, 256, 0, stream>>>(qkv, qw, kw, Qh, Kh);
  vtrans_kernel<<<dim3(32, 4, 4), 256, 0, stream>>>(qkv, Vt);
  attn_kernel<<<4096, 256, 0, stream>>>(Qh, Kh, Vt, Y);
  gemm_bt<false><<<dim3(64 * 8), 256, 0, stream>>>(Y, wob, (void*)outp, MROWS, DIMD, DIMD);
}

// Round 14
// 130.450 us; speedup vs baseline: 1.1888x; 1.1643x over previous
//
#include <hip/hip_runtime.h>
#include <hip/hip_bf16.h>

// Problem constants
#define DIMD 1024
#define NH   16
#define NKV  4
#define HDIM 64
#define WINSZ 512
#define BB   4
#define TT   2048
#define MROWS (BB*TT)      // 8192
#define NQKV 1536

typedef __attribute__((ext_vector_type(8))) short short8;
typedef __attribute__((ext_vector_type(4))) float f32x4;

static __device__ __forceinline__ short f2bf(float f) {
  __hip_bfloat16 h = __float2bfloat16(f);
  return __builtin_bit_cast(short, h);
}
static __device__ __forceinline__ float bf2f(short s) {
  return __bfloat162float(__builtin_bit_cast(__hip_bfloat16, s));
}
static __device__ __forceinline__ unsigned pk2(float a, float b) {
  unsigned lo = (unsigned short)f2bf(a);
  unsigned hi = (unsigned short)f2bf(b);
  return lo | (hi << 16);
}

static __device__ __forceinline__ void gld_lds16(const void* g, void* l) {
  __builtin_amdgcn_global_load_lds(
      (const __attribute__((address_space(1))) unsigned int*)g,
      (__attribute__((address_space(3))) unsigned int*)l, 16, 0, 0);
}

// DPP rotate-right within each 16-lane row
template<int N>
static __device__ __forceinline__ float dpp_ror(float x) {
  return __builtin_bit_cast(float, __builtin_amdgcn_update_dpp(
      0, __builtin_bit_cast(int, x), 0x120 + N, 0xF, 0xF, true));
}

// ---------------------------------------------------------------------------
// 1) f32 -> bf16 conversion for x, wq|wk|wv (packed), wo.  Unit = 4 floats.
__global__ __launch_bounds__(256) void cvt_all_kernel(
    const float* __restrict__ x, const float* __restrict__ wq,
    const float* __restrict__ wk, const float* __restrict__ wv,
    const float* __restrict__ wo,
    short* __restrict__ xb, short* __restrict__ wqkvb, short* __restrict__ wob) {
  size_t u = (size_t)blockIdx.x * 256 + threadIdx.x;
  const float* src; short* dst;
  if (u < 2097152)                   { src = x;  dst = xb; }
  else if ((u -= 2097152) < 262144)  { src = wq; dst = wqkvb; }
  else if ((u -= 262144) < 65536)    { src = wk; dst = wqkvb + 1024*1024; }
  else if ((u -= 65536) < 65536)     { src = wv; dst = wqkvb + 1280*1024; }
  else { u -= 65536;                   src = wo; dst = wob; }
  float4 v = ((const float4*)src)[u];
  short4 o;
  o.x = f2bf(v.x); o.y = f2bf(v.y); o.z = f2bf(v.z); o.w = f2bf(v.w);
  ((short4*)dst)[u] = o;
}

// ---------------------------------------------------------------------------
// 2) GEMM  C[M][N] = A[M][K] * B[N][K]^T   (bf16 in, bf16 or f32 out)
#define BMT 128
#define BNT 128
#define BKT 64

template<bool OUT_BF16>
__global__ __launch_bounds__(256) void gemm_bt(
    const short* __restrict__ A, const short* __restrict__ Bw,
    void* __restrict__ Cout, int M, int N, int K) {
  __shared__ __align__(16) short As[BMT*BKT];
  __shared__ __align__(16) short Bs[BNT*BKT];

  int nwg  = gridDim.x;
  int orig = blockIdx.x;
  int wg   = (orig & 7) * (nwg >> 3) + (orig >> 3);   // XCD swizzle (nwg%8==0)
  int tiles_n = N / BNT;
  int m0 = (wg / tiles_n) * BMT;
  int n0 = (wg % tiles_n) * BNT;

  int tid = threadIdx.x;
  int lane = tid & 63, wv = tid >> 6;
  int l15 = lane & 15, lg = lane >> 4;
  int wr = wv >> 1, wc = wv & 1;

  f32x4 acc[4][4] = {};

  for (int k0 = 0; k0 < K; k0 += BKT) {
    __syncthreads();
    const char* Abase = (const char*)(A + (size_t)m0 * K + k0);
    const char* Bbase = (const char*)(Bw + (size_t)n0 * K + k0);
#pragma unroll
    for (int i = 0; i < 4; ++i) {
      int idx = i * 256 + tid;
      int row = idx >> 3;
      int cb  = (idx & 7) << 4;
      int scb = cb ^ ((row & 7) << 4);
      gld_lds16(Abase + (size_t)row * (K * 2) + scb,
                (char*)As + ((i * 256 + wv * 64) << 4));
      gld_lds16(Bbase + (size_t)row * (K * 2) + scb,
                (char*)Bs + ((i * 256 + wv * 64) << 4));
    }
    __syncthreads();

#pragma unroll
    for (int kk = 0; kk < 2; ++kk) {
      short8 af[4], bfr[4];
      int kb = (kk * 32 + lg * 8) * 2;
#pragma unroll
      for (int mi = 0; mi < 4; ++mi) {
        int row = wr * 64 + mi * 16 + l15;
        af[mi] = *(const short8*)((const char*)As + row * 128 + (kb ^ ((row & 7) << 4)));
      }
#pragma unroll
      for (int ni = 0; ni < 4; ++ni) {
        int row = wc * 64 + ni * 16 + l15;
        bfr[ni] = *(const short8*)((const char*)Bs + row * 128 + (kb ^ ((row & 7) << 4)));
      }
#pragma unroll
      for (int mi = 0; mi < 4; ++mi)
#pragma unroll
        for (int ni = 0; ni < 4; ++ni)
          acc[mi][ni] = __builtin_amdgcn_mfma_f32_16x16x32_bf16(af[mi], bfr[ni], acc[mi][ni], 0, 0, 0);
    }
  }

  int crow0 = m0 + wr * 64, ccol0 = n0 + wc * 64;
#pragma unroll
  for (int mi = 0; mi < 4; ++mi)
#pragma unroll
    for (int ni = 0; ni < 4; ++ni)
#pragma unroll
      for (int r = 0; r < 4; ++r) {
        int row = crow0 + mi * 16 + lg * 4 + r;
        int col = ccol0 + ni * 16 + l15;
        float v = acc[mi][ni][r];
        if (OUT_BF16) ((short*)Cout)[(size_t)row * N + col] = f2bf(v);
        else          ((float*)Cout)[(size_t)row * N + col] = v;
      }
}

// ---------------------------------------------------------------------------
// 3) RMSNorm on q and k heads; one 16-lane group per head-row, lane holds 4.
__global__ __launch_bounds__(256) void qk_norm_kernel(
    const short* __restrict__ qkv, const float* __restrict__ qw,
    const float* __restrict__ kw, short* __restrict__ Qh, short* __restrict__ Kh) {
  unsigned gid = blockIdx.x * 16u + (threadIdx.x >> 4);
  int l = threadIdx.x & 15;
  unsigned row = gid / 20u;          // b*T + t
  int s = (int)(gid - row * 20u);    // head slot 0..19
  int b = row >> 11, t = row & 2047;
  bool isq = s < 16;
  int col = isq ? s * 64 : 1024 + (s - 16) * 64;
  const short* rp = qkv + (size_t)row * NQKV + col + l * 4;
  short4 v4 = *(const short4*)rp;
  float f0 = bf2f(v4.x), f1 = bf2f(v4.y), f2 = bf2f(v4.z), f3 = bf2f(v4.w);
  float ss = f0 * f0 + f1 * f1 + f2 * f2 + f3 * f3;
  ss += dpp_ror<1>(ss); ss += dpp_ror<2>(ss);
  ss += dpp_ror<4>(ss); ss += dpp_ror<8>(ss);
  float r = rsqrtf(ss * (1.0f / 64.0f) + 1e-6f);
  float4 w4 = *(const float4*)((isq ? qw : kw) + l * 4);
  short4 o;
  o.x = f2bf(f0 * r * w4.x); o.y = f2bf(f1 * r * w4.y);
  o.z = f2bf(f2 * r * w4.z); o.w = f2bf(f3 * r * w4.w);
  if (isq) *(short4*)(Qh + (((size_t)b * NH + s) * TT + t) * HDIM + l * 4) = o;
  else     *(short4*)(Kh + (((size_t)b * NKV + (s - 16)) * TT + t) * HDIM + l * 4) = o;
}

// ---------------------------------------------------------------------------
// 4) V transpose: qkv cols [1280..1536) -> Vt [B][KV][64][T] (bf16)
__global__ __launch_bounds__(256) void vtrans_kernel(
    const short* __restrict__ qkv, short* __restrict__ Vt) {
  int tb = blockIdx.x, kv = blockIdx.y, b = blockIdx.z;
  __shared__ short tile[64][72];
  int tid = threadIdx.x;
#pragma unroll
  for (int i = 0; i < 2; ++i) {
    int idx = i * 256 + tid;
    int tr = idx >> 3;
    int c8 = (idx & 7) * 8;
    int t = tb * 64 + tr;
    const short* src = qkv + (size_t)(b * TT + t) * NQKV + 1280 + kv * 64 + c8;
    short8 v = *(const short8*)src;
#pragma unroll
    for (int j = 0; j < 8; ++j) tile[tr][c8 + j] = v[j];
  }
  __syncthreads();
#pragma unroll
  for (int i = 0; i < 2; ++i) {
    int idx = i * 256 + tid;
    int d = idx >> 3;
    int t8 = (idx & 7) * 8;
    short8 o;
#pragma unroll
    for (int j = 0; j < 8; ++j) o[j] = tile[t8 + j][d];
    short* dst = Vt + (((size_t)(b * NKV + kv) * HDIM) + d) * TT + tb * 64 + t8;
    *(short8*)dst = o;
  }
}

// ---------------------------------------------------------------------------
// 5) Sliding-window causal flash attention (GQA).
//    BLOCK = (b, kvh, qh): 4 waves = the 4 q-heads of one GQA group, all
//    sharing the same 32-q window and the SAME K/V tiles.  Each wave owns
//    its full window (no k-split, no combine).  K tile (8KB) staged once
//    per block into LDS via global_load_lds (4 waves cooperative, m97
//    2-barrier pattern) with XOR-swizzle applied on the GLOBAL source
//    (linear LDS dest, rule 21); reads apply the same XOR -> conflict-free.
//    V loads stay per-wave from L2 (latency hidden under QK+softmax).
//    Swapped QK^T (P[k][q] k-major/lane), fixed-max softmax, setprio MFMA.
#define C1A 0.180336880f   // 0.125 * log2(e)
#define C2A 11.5415603f    // 8     * log2(e)

__global__ __launch_bounds__(256) void attn_kernel(
    const short* __restrict__ Qh, const short* __restrict__ Kh,
    const short* __restrict__ Vt, short* __restrict__ Y) {
  int wgid = blockIdx.x;
  int qh = wgid >> 4;                  // 0..63, SLOWEST (per-CU balance)
  int kvh = (wgid >> 2) & 3;
  int b = wgid & 3;
  int tid = threadIdx.x, lane = tid & 63, wv = tid >> 6;
  int l15 = lane & 15, lg = lane >> 4;
  int h = kvh * 4 + wv;                // this wave's q-head
  int q0 = qh * 32;
  const short* Qp = Qh + (((size_t)b * NH + h) * TT + q0) * HDIM;
  const char*  Kp = (const char*)(Kh + ((size_t)b * NKV + kvh) * TT * HDIM);
  const short* Vp = Vt + ((size_t)b * NKV + kvh) * HDIM * TT;

  short8 aqA0 = *(const short8*)(Qp + l15 * HDIM + lg * 8);
  short8 aqA1 = *(const short8*)(Qp + l15 * HDIM + 32 + lg * 8);
  short8 aqB0 = *(const short8*)(Qp + (16 + l15) * HDIM + lg * 8);
  short8 aqB1 = *(const short8*)(Qp + (16 + l15) * HDIM + 32 + lg * 8);

  float lpA = 0.f, lpB = 0.f;          // lane-scalar partials (q = l15)
  f32x4 yA[4] = {}, yB[4] = {};

  // LDS: K tile 8192 B + 4 x 4608 B per-wave P scratch = 26624 B
  __shared__ __align__(16) char smem[26624];
  char* Kbuf = smem;
  short* PA = (short*)(smem + 8192 + wv * 4608);
  short* PB = PA + 1152;

  int lo = q0 - (WINSZ - 1); if (lo < 0) lo = 0;
  int klo = lo & ~63;
  int nt = (q0 + 32 - klo + 63) >> 6;  // CEIL tile count

  int qiA = q0 + l15, qiB = qiA + 16;  // q index per lane (swapped layout)

  for (int t = 0; t < nt; ++t) {
    int kc = klo + t * 64;
    __syncthreads();                   // prior tile's K reads complete
    // ---- STAGE K tile: wave wv stages rows wv*16..wv*16+15 (2 x 1KB).
    //      LDS dest linear (base + lane*16); source pre-swizzled:
    //      LDS[rr][cb] = K[kc+rr][cb ^ ((rr&7)<<4)]
#pragma unroll
    for (int r = 0; r < 2; ++r) {
      int rr = wv * 16 + r * 8 + (lane >> 3);
      int cb = (lane & 7) * 16;
      gld_lds16(Kp + (size_t)(kc + rr) * 128 + (cb ^ ((rr & 7) << 4)),
                Kbuf + wv * 2048 + r * 1024);
    }
    __syncthreads();                   // vmcnt(0) drain: staging complete

    // ---- V fragments (L2, latency hidden under QK + softmax)
    short8 bv0[4], bv1[4];
#pragma unroll
    for (int dt = 0; dt < 4; ++dt) {
      const short* vb = Vp + (size_t)(dt * 16 + l15) * TT + kc + lg * 8;
      bv0[dt] = *(const short8*)vb;
      bv1[dt] = *(const short8*)(vb + 32);
    }
    // ---- K fragments from LDS (swizzled read: conflict-free)
    short8 bk0[4], bk1[4];
    int sw = (l15 & 7) << 4;
#pragma unroll
    for (int nc = 0; nc < 4; ++nc) {
      int rb = (nc * 16 + l15) * 128;
      bk0[nc] = *(const short8*)(Kbuf + rb + ((lg * 16) ^ sw));
      bk1[nc] = *(const short8*)(Kbuf + rb + ((lg * 16 + 64) ^ sw));
    }
    // ---- swapped QK^T: D[k][q]
    f32x4 sA[4], sB[4];
    __builtin_amdgcn_s_setprio(1);
#pragma unroll
    for (int nc = 0; nc < 4; ++nc) {
      f32x4 zA = {}, zB = {};
      zA = __builtin_amdgcn_mfma_f32_16x16x32_bf16(bk0[nc], aqA0, zA, 0, 0, 0);
      zB = __builtin_amdgcn_mfma_f32_16x16x32_bf16(bk0[nc], aqB0, zB, 0, 0, 0);
      zA = __builtin_amdgcn_mfma_f32_16x16x32_bf16(bk1[nc], aqA1, zA, 0, 0, 0);
      zB = __builtin_amdgcn_mfma_f32_16x16x32_bf16(bk1[nc], aqB1, zB, 0, 0, 0);
      sA[nc] = zA; sB[nc] = zB;
    }
    __builtin_amdgcn_s_setprio(0);
    // ---- fixed-max softmax, pack, vector LDS write (k-major per lane)
    bool intA = (kc >= q0 - 496) && (kc + 63 <= q0);
    bool intB = (kc >= q0 - 480) && (kc + 63 <= q0 + 16);
    if (intA && intB) {
#pragma unroll
      for (int nc = 0; nc < 4; ++nc) {
        float pa0 = __builtin_amdgcn_exp2f(fmaf(sA[nc][0], C1A, -C2A));
        float pa1 = __builtin_amdgcn_exp2f(fmaf(sA[nc][1], C1A, -C2A));
        float pa2 = __builtin_amdgcn_exp2f(fmaf(sA[nc][2], C1A, -C2A));
        float pa3 = __builtin_amdgcn_exp2f(fmaf(sA[nc][3], C1A, -C2A));
        float pb0 = __builtin_amdgcn_exp2f(fmaf(sB[nc][0], C1A, -C2A));
        float pb1 = __builtin_amdgcn_exp2f(fmaf(sB[nc][1], C1A, -C2A));
        float pb2 = __builtin_amdgcn_exp2f(fmaf(sB[nc][2], C1A, -C2A));
        float pb3 = __builtin_amdgcn_exp2f(fmaf(sB[nc][3], C1A, -C2A));
        lpA += (pa0 + pa1) + (pa2 + pa3);
        lpB += (pb0 + pb1) + (pb2 + pb3);
        *(uint2*)(PA + l15 * 72 + nc * 16 + lg * 4) = uint2{pk2(pa0, pa1), pk2(pa2, pa3)};
        *(uint2*)(PB + l15 * 72 + nc * 16 + lg * 4) = uint2{pk2(pb0, pb1), pk2(pb2, pb3)};
      }
    } else {
      int kjb = kc + lg * 4;
#pragma unroll
      for (int nc = 0; nc < 4; ++nc) {
        float pa[4], pb[4];
#pragma unroll
        for (int r = 0; r < 4; ++r) {
          int kj = kjb + nc * 16 + r;
          bool okA = (kj <= qiA) && (qiA - kj < WINSZ);
          bool okB = (kj <= qiB) && (qiB - kj < WINSZ);
          pa[r] = okA ? __builtin_amdgcn_exp2f(fmaf(sA[nc][r], C1A, -C2A)) : 0.f;
          pb[r] = okB ? __builtin_amdgcn_exp2f(fmaf(sB[nc][r], C1A, -C2A)) : 0.f;
        }
        lpA += (pa[0] + pa[1]) + (pa[2] + pa[3]);
        lpB += (pb[0] + pb[1]) + (pb[2] + pb[3]);
        *(uint2*)(PA + l15 * 72 + nc * 16 + lg * 4) = uint2{pk2(pa[0], pa[1]), pk2(pa[2], pa[3])};
        *(uint2*)(PB + l15 * 72 + nc * 16 + lg * 4) = uint2{pk2(pb[0], pb[1]), pk2(pb[2], pb[3])};
      }
    }
    // ---- PV A-fragments (per-wave LDS region, no barrier)
    short8 apA0 = *(const short8*)(PA + l15 * 72 + lg * 8);
    short8 apA1 = *(const short8*)(PA + l15 * 72 + 32 + lg * 8);
    short8 apB0 = *(const short8*)(PB + l15 * 72 + lg * 8);
    short8 apB1 = *(const short8*)(PB + l15 * 72 + 32 + lg * 8);
    __builtin_amdgcn_s_setprio(1);
#pragma unroll
    for (int dt = 0; dt < 4; ++dt) {
      yA[dt] = __builtin_amdgcn_mfma_f32_16x16x32_bf16(apA0, bv0[dt], yA[dt], 0, 0, 0);
      yB[dt] = __builtin_amdgcn_mfma_f32_16x16x32_bf16(apB0, bv0[dt], yB[dt], 0, 0, 0);
      yA[dt] = __builtin_amdgcn_mfma_f32_16x16x32_bf16(apA1, bv1[dt], yA[dt], 0, 0, 0);
      yB[dt] = __builtin_amdgcn_mfma_f32_16x16x32_bf16(apB1, bv1[dt], yB[dt], 0, 0, 0);
    }
    __builtin_amdgcn_s_setprio(0);
  }

  // ---- per-wave epilogue (wave owns its head completely; no combine)
  lpA += __shfl_xor(lpA, 16); lpA += __shfl_xor(lpA, 32);
  lpB += __shfl_xor(lpB, 16); lpB += __shfl_xor(lpB, 32);
  float invqA = 1.0f / lpA;            // q = l15
  float invqB = 1.0f / lpB;
#pragma unroll
  for (int r = 0; r < 4; ++r) {
    // redistribute: y rows are q = lg*4+r -> pull inv from lane (lg*4+r)
    float invA = __builtin_bit_cast(float, __builtin_amdgcn_ds_bpermute(
        (lg * 4 + r) << 2, __builtin_bit_cast(int, invqA)));
    float invB = __builtin_bit_cast(float, __builtin_amdgcn_ds_bpermute(
        (lg * 4 + r) << 2, __builtin_bit_cast(int, invqB)));
    int qiAo = q0 + lg * 4 + r, qiBo = qiAo + 16;
#pragma unroll
    for (int dt = 0; dt < 4; ++dt) {
      Y[((size_t)(b * TT + qiAo)) * DIMD + h * HDIM + dt * 16 + l15] = f2bf(yA[dt][r] * invA);
      Y[((size_t)(b * TT + qiBo)) * DIMD + h * HDIM + dt * 16 + l15] = f2bf(yB[dt][r] * invB);
    }
  }
}

// ---------------------------------------------------------------------------
extern "C" void kernel_launch(void* const* d_in, const int* in_sizes, int n_in,
                              void* d_out, int out_size, void* d_ws, size_t ws_size,
                              hipStream_t stream) {
  const float* x  = (const float*)d_in[0];
  const float* wq = (const float*)d_in[1];
  const float* wk = (const float*)d_in[2];
  const float* wv = (const float*)d_in[3];
  const float* wo = (const float*)d_in[4];
  const float* qw = (const float*)d_in[5];
  const float* kw = (const float*)d_in[6];

  char* ws = (char*)d_ws;
  short* xb    = (short*)(ws + 0);            // 16 MB  [8192][1024] bf16
  short* wqkvb = (short*)(ws + 16777216);     // 3 MB   [1536][1024]
  short* wob   = (short*)(ws + 19922944);     // 2 MB   [1024][1024]
  short* qkv   = (short*)(ws + 22020096);     // 24 MB  [8192][1536]
  short* Qh    = (short*)(ws + 47185920);     // 16 MB  [B][H][T][64]
  short* Kh    = (short*)(ws + 63963136);     // 4 MB   [B][KV][T][64]
  short* Vt    = (short*)(ws + 68157440);     // 4 MB   [B][KV][64][T]
  short* Y     = xb;                          // alias: xb dead after QKV GEMM
  float* outp  = (float*)d_out;

  cvt_all_kernel<<<10752, 256, 0, stream>>>(x, wq, wk, wv, wo, xb, wqkvb, wob);
  gemm_bt<true><<<dim3(64 * 12), 256, 0, stream>>>(xb, wqkvb, (void*)qkv, MROWS, NQKV, DIMD);
  qk_norm_kernel<<<10240, 256, 0, stream>>>(qkv, qw, kw, Qh, Kh);
  vtrans_kernel<<<dim3(32, 4, 4), 256, 0, stream>>>(qkv, Vt);
  attn_kernel<<<1024, 256, 0, stream>>>(Qh, Kh, Vt, Y);
  gemm_bt<false><<<dim3(64 * 8), 256, 0, stream>>>(Y, wob, (void*)outp, MROWS, DIMD, DIMD);
}

// Round 15
// 129.627 us; speedup vs baseline: 1.1964x; 1.0064x over previous
//
#include <hip/hip_runtime.h>
#include <hip/hip_bf16.h>

// Problem constants
#define DIMD 1024
#define NH   16
#define NKV  4
#define HDIM 64
#define WINSZ 512
#define BB   4
#define TT   2048
#define MROWS (BB*TT)      // 8192
#define NQKV 1536

typedef __attribute__((ext_vector_type(8))) short short8;
typedef __attribute__((ext_vector_type(4))) float f32x4;

static __device__ __forceinline__ short f2bf(float f) {
  __hip_bfloat16 h = __float2bfloat16(f);
  return __builtin_bit_cast(short, h);
}
static __device__ __forceinline__ float bf2f(short s) {
  return __bfloat162float(__builtin_bit_cast(__hip_bfloat16, s));
}
static __device__ __forceinline__ unsigned pk2(float a, float b) {
  unsigned lo = (unsigned short)f2bf(a);
  unsigned hi = (unsigned short)f2bf(b);
  return lo | (hi << 16);
}

static __device__ __forceinline__ void gld_lds16(const void* g, void* l) {
  __builtin_amdgcn_global_load_lds(
      (const __attribute__((address_space(1))) unsigned int*)g,
      (__attribute__((address_space(3))) unsigned int*)l, 16, 0, 0);
}

// DPP rotate-right within each 16-lane row
template<int N>
static __device__ __forceinline__ float dpp_ror(float x) {
  return __builtin_bit_cast(float, __builtin_amdgcn_update_dpp(
      0, __builtin_bit_cast(int, x), 0x120 + N, 0xF, 0xF, true));
}

// ---------------------------------------------------------------------------
// 1) f32 -> bf16 conversion for x, wq|wk|wv (packed), wo.  Unit = 4 floats.
__global__ __launch_bounds__(256) void cvt_all_kernel(
    const float* __restrict__ x, const float* __restrict__ wq,
    const float* __restrict__ wk, const float* __restrict__ wv,
    const float* __restrict__ wo,
    short* __restrict__ xb, short* __restrict__ wqkvb, short* __restrict__ wob) {
  size_t u = (size_t)blockIdx.x * 256 + threadIdx.x;
  const float* src; short* dst;
  if (u < 2097152)                   { src = x;  dst = xb; }
  else if ((u -= 2097152) < 262144)  { src = wq; dst = wqkvb; }
  else if ((u -= 262144) < 65536)    { src = wk; dst = wqkvb + 1024*1024; }
  else if ((u -= 65536) < 65536)     { src = wv; dst = wqkvb + 1280*1024; }
  else { u -= 65536;                   src = wo; dst = wob; }
  float4 v = ((const float4*)src)[u];
  short4 o;
  o.x = f2bf(v.x); o.y = f2bf(v.y); o.z = f2bf(v.z); o.w = f2bf(v.w);
  ((short4*)dst)[u] = o;
}

// ---------------------------------------------------------------------------
// 2) GEMM  C[M][N] = A[M][K] * B[N][K]^T   (bf16 in, bf16 or f32 out)
#define BMT 128
#define BNT 128
#define BKT 64

template<bool OUT_BF16>
__global__ __launch_bounds__(256) void gemm_bt(
    const short* __restrict__ A, const short* __restrict__ Bw,
    void* __restrict__ Cout, int M, int N, int K) {
  __shared__ __align__(16) short As[BMT*BKT];
  __shared__ __align__(16) short Bs[BNT*BKT];

  int nwg  = gridDim.x;
  int orig = blockIdx.x;
  int wg   = (orig & 7) * (nwg >> 3) + (orig >> 3);   // XCD swizzle (nwg%8==0)
  int tiles_n = N / BNT;
  int m0 = (wg / tiles_n) * BMT;
  int n0 = (wg % tiles_n) * BNT;

  int tid = threadIdx.x;
  int lane = tid & 63, wv = tid >> 6;
  int l15 = lane & 15, lg = lane >> 4;
  int wr = wv >> 1, wc = wv & 1;

  f32x4 acc[4][4] = {};

  for (int k0 = 0; k0 < K; k0 += BKT) {
    __syncthreads();
    const char* Abase = (const char*)(A + (size_t)m0 * K + k0);
    const char* Bbase = (const char*)(Bw + (size_t)n0 * K + k0);
#pragma unroll
    for (int i = 0; i < 4; ++i) {
      int idx = i * 256 + tid;
      int row = idx >> 3;
      int cb  = (idx & 7) << 4;
      int scb = cb ^ ((row & 7) << 4);
      gld_lds16(Abase + (size_t)row * (K * 2) + scb,
                (char*)As + ((i * 256 + wv * 64) << 4));
      gld_lds16(Bbase + (size_t)row * (K * 2) + scb,
                (char*)Bs + ((i * 256 + wv * 64) << 4));
    }
    __syncthreads();

#pragma unroll
    for (int kk = 0; kk < 2; ++kk) {
      short8 af[4], bfr[4];
      int kb = (kk * 32 + lg * 8) * 2;
#pragma unroll
      for (int mi = 0; mi < 4; ++mi) {
        int row = wr * 64 + mi * 16 + l15;
        af[mi] = *(const short8*)((const char*)As + row * 128 + (kb ^ ((row & 7) << 4)));
      }
#pragma unroll
      for (int ni = 0; ni < 4; ++ni) {
        int row = wc * 64 + ni * 16 + l15;
        bfr[ni] = *(const short8*)((const char*)Bs + row * 128 + (kb ^ ((row & 7) << 4)));
      }
#pragma unroll
      for (int mi = 0; mi < 4; ++mi)
#pragma unroll
        for (int ni = 0; ni < 4; ++ni)
          acc[mi][ni] = __builtin_amdgcn_mfma_f32_16x16x32_bf16(af[mi], bfr[ni], acc[mi][ni], 0, 0, 0);
    }
  }

  int crow0 = m0 + wr * 64, ccol0 = n0 + wc * 64;
#pragma unroll
  for (int mi = 0; mi < 4; ++mi)
#pragma unroll
    for (int ni = 0; ni < 4; ++ni)
#pragma unroll
      for (int r = 0; r < 4; ++r) {
        int row = crow0 + mi * 16 + lg * 4 + r;
        int col = ccol0 + ni * 16 + l15;
        float v = acc[mi][ni][r];
        if (OUT_BF16) ((short*)Cout)[(size_t)row * N + col] = f2bf(v);
        else          ((float*)Cout)[(size_t)row * N + col] = v;
      }
}

// ---------------------------------------------------------------------------
// 3) RMSNorm on q and k heads; one 16-lane group per head-row, lane holds 4.
__global__ __launch_bounds__(256) void qk_norm_kernel(
    const short* __restrict__ qkv, const float* __restrict__ qw,
    const float* __restrict__ kw, short* __restrict__ Qh, short* __restrict__ Kh) {
  unsigned gid = blockIdx.x * 16u + (threadIdx.x >> 4);
  int l = threadIdx.x & 15;
  unsigned row = gid / 20u;          // b*T + t
  int s = (int)(gid - row * 20u);    // head slot 0..19
  int b = row >> 11, t = row & 2047;
  bool isq = s < 16;
  int col = isq ? s * 64 : 1024 + (s - 16) * 64;
  const short* rp = qkv + (size_t)row * NQKV + col + l * 4;
  short4 v4 = *(const short4*)rp;
  float f0 = bf2f(v4.x), f1 = bf2f(v4.y), f2 = bf2f(v4.z), f3 = bf2f(v4.w);
  float ss = f0 * f0 + f1 * f1 + f2 * f2 + f3 * f3;
  ss += dpp_ror<1>(ss); ss += dpp_ror<2>(ss);
  ss += dpp_ror<4>(ss); ss += dpp_ror<8>(ss);
  float r = rsqrtf(ss * (1.0f / 64.0f) + 1e-6f);
  float4 w4 = *(const float4*)((isq ? qw : kw) + l * 4);
  short4 o;
  o.x = f2bf(f0 * r * w4.x); o.y = f2bf(f1 * r * w4.y);
  o.z = f2bf(f2 * r * w4.z); o.w = f2bf(f3 * r * w4.w);
  if (isq) *(short4*)(Qh + (((size_t)b * NH + s) * TT + t) * HDIM + l * 4) = o;
  else     *(short4*)(Kh + (((size_t)b * NKV + (s - 16)) * TT + t) * HDIM + l * 4) = o;
}

// ---------------------------------------------------------------------------
// 4) V transpose: qkv cols [1280..1536) -> Vt [B][KV][64][T] (bf16)
__global__ __launch_bounds__(256) void vtrans_kernel(
    const short* __restrict__ qkv, short* __restrict__ Vt) {
  int tb = blockIdx.x, kv = blockIdx.y, b = blockIdx.z;
  __shared__ short tile[64][72];
  int tid = threadIdx.x;
#pragma unroll
  for (int i = 0; i < 2; ++i) {
    int idx = i * 256 + tid;
    int tr = idx >> 3;
    int c8 = (idx & 7) * 8;
    int t = tb * 64 + tr;
    const short* src = qkv + (size_t)(b * TT + t) * NQKV + 1280 + kv * 64 + c8;
    short8 v = *(const short8*)src;
#pragma unroll
    for (int j = 0; j < 8; ++j) tile[tr][c8 + j] = v[j];
  }
  __syncthreads();
#pragma unroll
  for (int i = 0; i < 2; ++i) {
    int idx = i * 256 + tid;
    int d = idx >> 3;
    int t8 = (idx & 7) * 8;
    short8 o;
#pragma unroll
    for (int j = 0; j < 8; ++j) o[j] = tile[t8 + j][d];
    short* dst = Vt + (((size_t)(b * NKV + kv) * HDIM) + d) * TT + tb * 64 + t8;
    *(short8*)dst = o;
  }
}

// ---------------------------------------------------------------------------
// 5) Sliding-window causal flash attention (GQA).
//    BLOCK = (b, kvh, qh): 4 waves = the 4 q-heads of one GQA group sharing
//    the same 32-q window and K tiles.  K staged once per block into LDS.
//    NEW (r15): 2-phase K double-buffer — stage(t+1) issued BEFORE
//    compute(t), single barrier per tile drains it after compute (T3
//    minimum pipeline; removes the serial stage->drain->compute chain).
//    XOR-swizzle on global source, linear LDS dest, swizzled read (rule 21).
//    Swapped QK^T (P[k][q] k-major/lane), fixed-max softmax, setprio MFMA.
#define C1A 0.180336880f   // 0.125 * log2(e)
#define C2A 11.5415603f    // 8     * log2(e)

__global__ __launch_bounds__(256) void attn_kernel(
    const short* __restrict__ Qh, const short* __restrict__ Kh,
    const short* __restrict__ Vt, short* __restrict__ Y) {
  int wgid = blockIdx.x;
  int qh = wgid >> 4;                  // 0..63, SLOWEST (per-CU balance)
  int kvh = (wgid >> 2) & 3;
  int b = wgid & 3;
  int tid = threadIdx.x, lane = tid & 63, wv = tid >> 6;
  int l15 = lane & 15, lg = lane >> 4;
  int h = kvh * 4 + wv;                // this wave's q-head
  int q0 = qh * 32;
  const short* Qp = Qh + (((size_t)b * NH + h) * TT + q0) * HDIM;
  const char*  Kp = (const char*)(Kh + ((size_t)b * NKV + kvh) * TT * HDIM);
  const short* Vp = Vt + ((size_t)b * NKV + kvh) * HDIM * TT;

  short8 aqA0 = *(const short8*)(Qp + l15 * HDIM + lg * 8);
  short8 aqA1 = *(const short8*)(Qp + l15 * HDIM + 32 + lg * 8);
  short8 aqB0 = *(const short8*)(Qp + (16 + l15) * HDIM + lg * 8);
  short8 aqB1 = *(const short8*)(Qp + (16 + l15) * HDIM + 32 + lg * 8);

  float lpA = 0.f, lpB = 0.f;          // lane-scalar partials (q = l15)
  f32x4 yA[4] = {}, yB[4] = {};

  // LDS: 2 x 8192 B K double-buffer + 4 x 4608 B per-wave P = 34816 B
  __shared__ __align__(16) char smem[34816];
  char* Kbuf = smem;
  short* PA = (short*)(smem + 16384 + wv * 4608);
  short* PB = PA + 1152;

  int lo = q0 - (WINSZ - 1); if (lo < 0) lo = 0;
  int klo = lo & ~63;
  int nt = (q0 + 32 - klo + 63) >> 6;  // CEIL tile count

  int qiA = q0 + l15, qiB = qiA + 16;  // q index per lane (swapped layout)

  // Wave wv stages rows wv*16..wv*16+15 (2 x 1KB gld_lds).  LDS dest is
  // linear (base + lane*16); the XOR swizzle is applied on the GLOBAL src:
  // LDS[rr][cb] = K[kc+rr][cb ^ ((rr&7)<<4)].
  auto STAGEK = [&](int kc, int bufsel) {
#pragma unroll
    for (int r = 0; r < 2; ++r) {
      int rr = wv * 16 + r * 8 + (lane >> 3);
      int cb = (lane & 7) * 16;
      gld_lds16(Kp + (size_t)(kc + rr) * 128 + (cb ^ ((rr & 7) << 4)),
                Kbuf + bufsel * 8192 + wv * 2048 + r * 1024);
    }
  };

  int cur = 0;
  STAGEK(klo, 0);
  __syncthreads();                     // drain first stage

  for (int t = 0; t < nt; ++t) {
    int kc = klo + t * 64;
    if (t + 1 < nt) STAGEK(kc + 64, cur ^ 1);   // issue next tile's stage

    const char* kbase = Kbuf + (cur << 13);
    // ---- V fragments (L2, latency hidden under QK + softmax)
    short8 bv0[4], bv1[4];
#pragma unroll
    for (int dt = 0; dt < 4; ++dt) {
      const short* vb = Vp + (size_t)(dt * 16 + l15) * TT + kc + lg * 8;
      bv0[dt] = *(const short8*)vb;
      bv1[dt] = *(const short8*)(vb + 32);
    }
    // ---- K fragments from LDS (swizzled read: conflict-free)
    short8 bk0[4], bk1[4];
    int sw = (l15 & 7) << 4;
#pragma unroll
    for (int nc = 0; nc < 4; ++nc) {
      int rb = (nc * 16 + l15) * 128;
      bk0[nc] = *(const short8*)(kbase + rb + ((lg * 16) ^ sw));
      bk1[nc] = *(const short8*)(kbase + rb + ((lg * 16 + 64) ^ sw));
    }
    // ---- swapped QK^T: D[k][q]
    f32x4 sA[4], sB[4];
    __builtin_amdgcn_s_setprio(1);
#pragma unroll
    for (int nc = 0; nc < 4; ++nc) {
      f32x4 zA = {}, zB = {};
      zA = __builtin_amdgcn_mfma_f32_16x16x32_bf16(bk0[nc], aqA0, zA, 0, 0, 0);
      zB = __builtin_amdgcn_mfma_f32_16x16x32_bf16(bk0[nc], aqB0, zB, 0, 0, 0);
      zA = __builtin_amdgcn_mfma_f32_16x16x32_bf16(bk1[nc], aqA1, zA, 0, 0, 0);
      zB = __builtin_amdgcn_mfma_f32_16x16x32_bf16(bk1[nc], aqB1, zB, 0, 0, 0);
      sA[nc] = zA; sB[nc] = zB;
    }
    __builtin_amdgcn_s_setprio(0);
    // ---- fixed-max softmax, pack, vector LDS write (k-major per lane)
    bool intA = (kc >= q0 - 496) && (kc + 63 <= q0);
    bool intB = (kc >= q0 - 480) && (kc + 63 <= q0 + 16);
    if (intA && intB) {
#pragma unroll
      for (int nc = 0; nc < 4; ++nc) {
        float pa0 = __builtin_amdgcn_exp2f(fmaf(sA[nc][0], C1A, -C2A));
        float pa1 = __builtin_amdgcn_exp2f(fmaf(sA[nc][1], C1A, -C2A));
        float pa2 = __builtin_amdgcn_exp2f(fmaf(sA[nc][2], C1A, -C2A));
        float pa3 = __builtin_amdgcn_exp2f(fmaf(sA[nc][3], C1A, -C2A));
        float pb0 = __builtin_amdgcn_exp2f(fmaf(sB[nc][0], C1A, -C2A));
        float pb1 = __builtin_amdgcn_exp2f(fmaf(sB[nc][1], C1A, -C2A));
        float pb2 = __builtin_amdgcn_exp2f(fmaf(sB[nc][2], C1A, -C2A));
        float pb3 = __builtin_amdgcn_exp2f(fmaf(sB[nc][3], C1A, -C2A));
        lpA += (pa0 + pa1) + (pa2 + pa3);
        lpB += (pb0 + pb1) + (pb2 + pb3);
        *(uint2*)(PA + l15 * 72 + nc * 16 + lg * 4) = uint2{pk2(pa0, pa1), pk2(pa2, pa3)};
        *(uint2*)(PB + l15 * 72 + nc * 16 + lg * 4) = uint2{pk2(pb0, pb1), pk2(pb2, pb3)};
      }
    } else {
      int kjb = kc + lg * 4;
#pragma unroll
      for (int nc = 0; nc < 4; ++nc) {
        float pa[4], pb[4];
#pragma unroll
        for (int r = 0; r < 4; ++r) {
          int kj = kjb + nc * 16 + r;
          bool okA = (kj <= qiA) && (qiA - kj < WINSZ);
          bool okB = (kj <= qiB) && (qiB - kj < WINSZ);
          pa[r] = okA ? __builtin_amdgcn_exp2f(fmaf(sA[nc][r], C1A, -C2A)) : 0.f;
          pb[r] = okB ? __builtin_amdgcn_exp2f(fmaf(sB[nc][r], C1A, -C2A)) : 0.f;
        }
        lpA += (pa[0] + pa[1]) + (pa[2] + pa[3]);
        lpB += (pb[0] + pb[1]) + (pb[2] + pb[3]);
        *(uint2*)(PA + l15 * 72 + nc * 16 + lg * 4) = uint2{pk2(pa[0], pa[1]), pk2(pa[2], pa[3])};
        *(uint2*)(PB + l15 * 72 + nc * 16 + lg * 4) = uint2{pk2(pb[0], pb[1]), pk2(pb[2], pb[3])};
      }
    }
    // ---- PV A-fragments (per-wave LDS region, no barrier)
    short8 apA0 = *(const short8*)(PA + l15 * 72 + lg * 8);
    short8 apA1 = *(const short8*)(PA + l15 * 72 + 32 + lg * 8);
    short8 apB0 = *(const short8*)(PB + l15 * 72 + lg * 8);
    short8 apB1 = *(const short8*)(PB + l15 * 72 + 32 + lg * 8);
    __builtin_amdgcn_s_setprio(1);
#pragma unroll
    for (int dt = 0; dt < 4; ++dt) {
      yA[dt] = __builtin_amdgcn_mfma_f32_16x16x32_bf16(apA0, bv0[dt], yA[dt], 0, 0, 0);
      yB[dt] = __builtin_amdgcn_mfma_f32_16x16x32_bf16(apB0, bv0[dt], yB[dt], 0, 0, 0);
      yA[dt] = __builtin_amdgcn_mfma_f32_16x16x32_bf16(apA1, bv1[dt], yA[dt], 0, 0, 0);
      yB[dt] = __builtin_amdgcn_mfma_f32_16x16x32_bf16(apB1, bv1[dt], yB[dt], 0, 0, 0);
    }
    __builtin_amdgcn_s_setprio(0);

    if (t + 1 < nt) __syncthreads();   // drains stage(t+1); syncs buf reuse
    cur ^= 1;
  }

  // ---- per-wave epilogue (wave owns its head completely; no combine)
  lpA += __shfl_xor(lpA, 16); lpA += __shfl_xor(lpA, 32);
  lpB += __shfl_xor(lpB, 16); lpB += __shfl_xor(lpB, 32);
  float invqA = 1.0f / lpA;            // q = l15
  float invqB = 1.0f / lpB;
#pragma unroll
  for (int r = 0; r < 4; ++r) {
    // redistribute: y rows are q = lg*4+r -> pull inv from lane (lg*4+r)
    float invA = __builtin_bit_cast(float, __builtin_amdgcn_ds_bpermute(
        (lg * 4 + r) << 2, __builtin_bit_cast(int, invqA)));
    float invB = __builtin_bit_cast(float, __builtin_amdgcn_ds_bpermute(
        (lg * 4 + r) << 2, __builtin_bit_cast(int, invqB)));
    int qiAo = q0 + lg * 4 + r, qiBo = qiAo + 16;
#pragma unroll
    for (int dt = 0; dt < 4; ++dt) {
      Y[((size_t)(b * TT + qiAo)) * DIMD + h * HDIM + dt * 16 + l15] = f2bf(yA[dt][r] * invA);
      Y[((size_t)(b * TT + qiBo)) * DIMD + h * HDIM + dt * 16 + l15] = f2bf(yB[dt][r] * invB);
    }
  }
}

// ---------------------------------------------------------------------------
extern "C" void kernel_launch(void* const* d_in, const int* in_sizes, int n_in,
                              void* d_out, int out_size, void* d_ws, size_t ws_size,
                              hipStream_t stream) {
  const float* x  = (const float*)d_in[0];
  const float* wq = (const float*)d_in[1];
  const float* wk = (const float*)d_in[2];
  const float* wv = (const float*)d_in[3];
  const float* wo = (const float*)d_in[4];
  const float* qw = (const float*)d_in[5];
  const float* kw = (const float*)d_in[6];

  char* ws = (char*)d_ws;
  short* xb    = (short*)(ws + 0);            // 16 MB  [8192][1024] bf16
  short* wqkvb = (short*)(ws + 16777216);     // 3 MB   [1536][1024]
  short* wob   = (short*)(ws + 19922944);     // 2 MB   [1024][1024]
  short* qkv   = (short*)(ws + 22020096);     // 24 MB  [8192][1536]
  short* Qh    = (short*)(ws + 47185920);     // 16 MB  [B][H][T][64]
  short* Kh    = (short*)(ws + 63963136);     // 4 MB   [B][KV][T][64]
  short* Vt    = (short*)(ws + 68157440);     // 4 MB   [B][KV][64][T]
  short* Y     = xb;                          // alias: xb dead after QKV GEMM
  float* outp  = (float*)d_out;

  cvt_all_kernel<<<10752, 256, 0, stream>>>(x, wq, wk, wv, wo, xb, wqkvb, wob);
  gemm_bt<true><<<dim3(64 * 12), 256, 0, stream>>>(xb, wqkvb, (void*)qkv, MROWS, NQKV, DIMD);
  qk_norm_kernel<<<10240, 256, 0, stream>>>(qkv, qw, kw, Qh, Kh);
  vtrans_kernel<<<dim3(32, 4, 4), 256, 0, stream>>>(qkv, Vt);
  attn_kernel<<<1024, 256, 0, stream>>>(Qh, Kh, Vt, Y);
  gemm_bt<false><<<dim3(64 * 8), 256, 0, stream>>>(Y, wob, (void*)outp, MROWS, DIMD, DIMD);
}